// Round 7
// baseline (215.448 us; speedup 1.0000x reference)
//
#include <hip/hip_runtime.h>
#include <math.h>

#define HH 2048
#define WW 2048
#define HWSZ (HH*WW)
#define RBOX 60
#define NBINS 2048
#define KTOP 4194
#define OMEGA 0.95f
#define T0C 0.1f
#define GFEPS 1e-4f
#define SEGV 16
// LDS bank-conflict-killing swizzle: accesses of form 8i+c map to 9i+c' -> all 32 banks
#define SW(i) ((i) + ((i) >> 3))
#define LDSN (WW + WW / 8)

struct UdcpState {
    int hist[NBINS];
    float tau;
    int A_bits[3];
};

// bf16 pair pack (round-to-nearest-even; truncation would bias cov -> bad a)
__device__ __forceinline__ unsigned pbf2(float lo, float hi) {
    unsigned ul = __float_as_uint(lo), uh = __float_as_uint(hi);
    ul += 0x7FFFu + ((ul >> 16) & 1u);
    uh += 0x7FFFu + ((uh >> 16) & 1u);
    return (ul >> 16) | (uh & 0xFFFF0000u);
}
__device__ __forceinline__ float ublo(unsigned u) { return __uint_as_float(u << 16); }
__device__ __forceinline__ float ubhi(unsigned u) { return __uint_as_float(u & 0xFFFF0000u); }

// ---------- vertical 15-min of G and B separately -> packed bf16 pair ----------
__global__ __launch_bounds__(256) void k_minv8_gb2(const float* __restrict__ x,
                                                   unsigned* __restrict__ mgb) {
    int xx = blockIdx.x * 256 + threadIdx.x;
    int y0 = blockIdx.y * 8;
    float rg[22], rb[22];
#pragma unroll
    for (int j = 0; j < 22; ++j) {
        int y = y0 + j - 7;
        int yc = min(max(y, 0), HH - 1);
        int i = yc * WW + xx;
        float g = x[HWSZ + i], b = x[2 * HWSZ + i];
        bool ok = (y >= 0) && (y < HH);
        rg[j] = ok ? g : 1e30f;
        rb[j] = ok ? b : 1e30f;
    }
    float sg[15], sb[15];
    sg[14] = rg[14]; sb[14] = rb[14];
#pragma unroll
    for (int j = 13; j >= 0; --j) {
        sg[j] = fminf(rg[j], sg[j + 1]);
        sb[j] = fminf(rb[j], sb[j + 1]);
    }
    float pg = 1e30f, pb = 1e30f;
#pragma unroll
    for (int j = 0; j < 8; ++j) {
        float mg = fminf(sg[j], pg), mb = fminf(sb[j], pb);
        mgb[(y0 + j) * WW + xx] = pbf2(mg, mb);
        if (j < 7) { pg = fminf(pg, rg[15 + j]); pb = fminf(pb, rb[15 + j]); }
    }
}

// ---------- horizontal 15-min of min(mgv,mbv) -> dc, fused histogram ----------
__global__ __launch_bounds__(256) void k_minh8_dc(const unsigned* __restrict__ mgb,
                                                  float* __restrict__ dc,
                                                  UdcpState* st) {
    __shared__ int h[NBINS];
    for (int j = threadIdx.x; j < NBINS; j += 256) h[j] = 0;
    __syncthreads();
    int row = blockIdx.x;
    int xb = threadIdx.x * 8;
    const unsigned* rp = mgb + row * WW;
    float r[22];
#pragma unroll
    for (int j = 0; j < 22; ++j) {
        int xc = min(max(xb + j - 7, 0), WW - 1);
        unsigned u = rp[xc];
        float v = fminf(ublo(u), ubhi(u));
        bool ok = (xb + j - 7 >= 0) && (xb + j - 7 < WW);
        r[j] = ok ? v : 1e30f;
    }
    float suf[15];
    suf[14] = r[14];
#pragma unroll
    for (int j = 13; j >= 0; --j) suf[j] = fminf(r[j], suf[j + 1]);
    float pre = 1e30f;
    float o[8];
#pragma unroll
    for (int j = 0; j < 8; ++j) {
        o[j] = fminf(suf[j], pre);
        if (j < 7) pre = fminf(pre, r[15 + j]);
    }
    float* dr = dc + row * WW + xb;
    *(float4*)dr = make_float4(o[0], o[1], o[2], o[3]);
    *(float4*)(dr + 4) = make_float4(o[4], o[5], o[6], o[7]);
#pragma unroll
    for (int j = 0; j < 8; ++j) {
        int b = (int)(o[j] * (float)NBINS);
        b = min(max(b, 0), NBINS - 1);
        atomicAdd(&h[b], 1);
    }
    __syncthreads();
    for (int j = threadIdx.x; j < NBINS; j += 256) {
        int v = h[j];
        if (v) atomicAdd(&st->hist[j], v);
    }
}

// ---------- k-th largest bin lower edge ----------
__global__ void k_tau(UdcpState* st) {
    __shared__ int csum[256];
    int tid = threadIdx.x;
    int hi = NBINS - 1 - 8 * tid;
    int local = 0;
    for (int k = 0; k < 8; ++k) local += st->hist[hi - k];
    csum[tid] = local;
    __syncthreads();
    if (tid == 0) {
        int cum = 0;
        float tau = 0.f;
        bool done = false;
        for (int c = 0; c < 256 && !done; ++c) {
            if (cum + csum[c] >= KTOP) {
                int h2 = NBINS - 1 - 8 * c;
                int cc = cum;
                for (int k = 0; k < 8; ++k) {
                    cc += st->hist[h2 - k];
                    if (cc >= KTOP) {
                        tau = (float)(h2 - k) / (float)NBINS;
                        done = true;
                        break;
                    }
                }
            } else {
                cum += csum[c];
            }
        }
        st->tau = tau;
    }
}

// ---------- atmospheric light: block-level reduce, few atomics ----------
__global__ __launch_bounds__(256) void k_A2(const float* __restrict__ dc,
                                            const float* __restrict__ x,
                                            UdcpState* st) {
    __shared__ float r0[256], r1[256], r2[256];
    __shared__ int anyflag;
    if (threadIdx.x == 0) anyflag = 0;
    __syncthreads();
    float tau = st->tau;
    const float4* dc4 = (const float4*)dc;
    int base4 = blockIdx.x * 1024;
    float m0 = -1e30f, m1 = -1e30f, m2 = -1e30f;
    bool found = false;
#pragma unroll
    for (int k = 0; k < 4; ++k) {
        int q = base4 + k * 256 + threadIdx.x;
        float4 v = dc4[q];
        float dv[4] = {v.x, v.y, v.z, v.w};
#pragma unroll
        for (int c = 0; c < 4; ++c) {
            if (dv[c] >= tau) {
                int i = q * 4 + c;
                m0 = fmaxf(m0, x[i]);
                m1 = fmaxf(m1, x[HWSZ + i]);
                m2 = fmaxf(m2, x[2 * HWSZ + i]);
                found = true;
            }
        }
    }
    if (found) anyflag = 1;
    __syncthreads();
    if (!anyflag) return;
    r0[threadIdx.x] = m0; r1[threadIdx.x] = m1; r2[threadIdx.x] = m2;
    __syncthreads();
    for (int s = 128; s > 0; s >>= 1) {
        if (threadIdx.x < s) {
            r0[threadIdx.x] = fmaxf(r0[threadIdx.x], r0[threadIdx.x + s]);
            r1[threadIdx.x] = fmaxf(r1[threadIdx.x], r1[threadIdx.x + s]);
            r2[threadIdx.x] = fmaxf(r2[threadIdx.x], r2[threadIdx.x + s]);
        }
        __syncthreads();
    }
    if (threadIdx.x == 0 && r0[0] > -1e29f) {
        atomicMax(&st->A_bits[0], __float_as_int(r0[0]));
        atomicMax(&st->A_bits[1], __float_as_int(r1[0]));
        atomicMax(&st->A_bits[2], __float_as_int(r2[0]));
    }
}

// ---------- fused: s from (mgv,mbv), h-min -> t, 121-box prefix on 4 fields ----------
// All LDS accesses swizzled via SW() -> conflict-free (stride-8 becomes stride-9)
__global__ __launch_bounds__(256) void k_boxh4f2(
        const float* __restrict__ x, const unsigned* __restrict__ mgb,
        const UdcpState* __restrict__ st, uint2* __restrict__ h4) {
    __shared__ float P0[LDSN], P1[LDSN], P2[LDSN], P3[LDSN];
    __shared__ float mrow[LDSN];
    __shared__ float wtot[4][4];
    int tid = threadIdx.x;
    int base = blockIdx.x * WW + tid * 8;
    int xb = tid * 8;
    float iA1 = 1.0f / __int_as_float(st->A_bits[1]);
    float iA2 = 1.0f / __int_as_float(st->A_bits[2]);
    {
        uint4 ua = *(const uint4*)(mgb + base);
        uint4 ub = *(const uint4*)(mgb + base + 4);
        unsigned uu[8] = {ua.x, ua.y, ua.z, ua.w, ub.x, ub.y, ub.z, ub.w};
#pragma unroll
        for (int j = 0; j < 8; ++j)
            mrow[SW(xb + j)] = fminf(ublo(uu[j]) * iA1, ubhi(uu[j]) * iA2);
    }
    float4 Ra = *(const float4*)(x + base), Rb = *(const float4*)(x + base + 4);
    float4 Ga = *(const float4*)(x + HWSZ + base), Gb = *(const float4*)(x + HWSZ + base + 4);
    float4 Ba = *(const float4*)(x + 2 * HWSZ + base), Bb = *(const float4*)(x + 2 * HWSZ + base + 4);
    float Rv[8] = {Ra.x, Ra.y, Ra.z, Ra.w, Rb.x, Rb.y, Rb.z, Rb.w};
    float Gv[8] = {Ga.x, Ga.y, Ga.z, Ga.w, Gb.x, Gb.y, Gb.z, Gb.w};
    float Bv[8] = {Ba.x, Ba.y, Ba.z, Ba.w, Bb.x, Bb.y, Bb.z, Bb.w};
    __syncthreads();
    float tv[8];
    {
        float r[22];
#pragma unroll
        for (int j = 0; j < 22; ++j) {
            int xc = min(max(xb + j - 7, 0), WW - 1);
            float v = mrow[SW(xc)];
            bool ok = (xb + j - 7 >= 0) && (xb + j - 7 < WW);
            r[j] = ok ? v : 1e30f;
        }
        float suf[15];
        suf[14] = r[14];
#pragma unroll
        for (int j = 13; j >= 0; --j) suf[j] = fminf(r[j], suf[j + 1]);
        float pre = 1e30f;
#pragma unroll
        for (int j = 0; j < 8; ++j) {
            tv[j] = 1.0f - OMEGA * fminf(suf[j], pre);
            if (j < 7) pre = fminf(pre, r[15 + j]);
        }
    }
    float gv[8];
#pragma unroll
    for (int j = 0; j < 8; ++j)
        gv[j] = 0.299f * Rv[j] + 0.587f * Gv[j] + 0.114f * Bv[j];
    float e0[8], e1[8], e2[8], e3[8];
    float s0 = 0.f, s1 = 0.f, s2 = 0.f, s3 = 0.f;
#pragma unroll
    for (int j = 0; j < 8; ++j) {
        s0 += gv[j]; e0[j] = s0;
        s1 += tv[j]; e1[j] = s1;
        s2 += gv[j] * tv[j]; e2[j] = s2;
        s3 += gv[j] * gv[j]; e3[j] = s3;
    }
    int lane = tid & 63, wv = tid >> 6;
    float i0 = s0, i1 = s1, i2 = s2, i3 = s3;
#pragma unroll
    for (int d = 1; d < 64; d <<= 1) {
        float u0 = __shfl_up(i0, d), u1 = __shfl_up(i1, d);
        float u2 = __shfl_up(i2, d), u3 = __shfl_up(i3, d);
        if (lane >= d) { i0 += u0; i1 += u1; i2 += u2; i3 += u3; }
    }
    if (lane == 63) {
        wtot[wv][0] = i0; wtot[wv][1] = i1; wtot[wv][2] = i2; wtot[wv][3] = i3;
    }
    __syncthreads();
    float off0 = i0 - s0, off1 = i1 - s1, off2 = i2 - s2, off3 = i3 - s3;
    for (int w = 0; w < wv; ++w) {
        off0 += wtot[w][0]; off1 += wtot[w][1];
        off2 += wtot[w][2]; off3 += wtot[w][3];
    }
#pragma unroll
    for (int j = 0; j < 8; ++j) {
        int sw = SW(xb + j);
        P0[sw] = e0[j] + off0;
        P1[sw] = e1[j] + off1;
        P2[sw] = e2[j] + off2;
        P3[sw] = e3[j] + off3;
    }
    __syncthreads();
#pragma unroll
    for (int j = 0; j < 8; ++j) {
        int xx = xb + j;
        int hi = SW(min(xx + RBOX, WW - 1));
        int lo = xx - RBOX - 1;
        float b0 = 0.f, b1 = 0.f, b2 = 0.f, b3 = 0.f;
        if (lo >= 0) {
            int ls = SW(lo);
            b0 = P0[ls]; b1 = P1[ls]; b2 = P2[ls]; b3 = P3[ls];
        }
        h4[base + j] = make_uint2(pbf2(P0[hi] - b0, P1[hi] - b1),
                                  pbf2(P2[hi] - b2, P3[hi] - b3));
    }
}

// ---------- vertical running-sum 121-box on packed fields + a/b ----------
// 4-chain split init (MLP), batched add/sub rows pinned with sched_barrier
__global__ __launch_bounds__(256) void k_boxv4(const uint2* __restrict__ h4,
                                               unsigned* __restrict__ ab) {
    int xx = blockIdx.x * 256 + threadIdx.x;
    int y0 = blockIdx.y * SEGV;
    float a0[4] = {0.f, 0.f, 0.f, 0.f}, a1[4] = {0.f, 0.f, 0.f, 0.f};
    float a2[4] = {0.f, 0.f, 0.f, 0.f}, a3[4] = {0.f, 0.f, 0.f, 0.f};
#pragma unroll 16
    for (int j = 0; j <= 2 * RBOX; ++j) {
        int yy = y0 - RBOX + j;
        int yc = min(max(yy, 0), HH - 1);
        uint2 v = h4[yc * WW + xx];
        bool ok = (yy >= 0) && (yy < HH);
        int c = j & 3;
        a0[c] += ok ? ublo(v.x) : 0.f;
        a1[c] += ok ? ubhi(v.x) : 0.f;
        a2[c] += ok ? ublo(v.y) : 0.f;
        a3[c] += ok ? ubhi(v.y) : 0.f;
    }
    float s0 = (a0[0] + a0[1]) + (a0[2] + a0[3]);
    float s1 = (a1[0] + a1[1]) + (a1[2] + a1[3]);
    float s2 = (a2[0] + a2[1]) + (a2[2] + a2[3]);
    float s3 = (a3[0] + a3[1]) + (a3[2] + a3[3]);
    uint2 VA[SEGV], VS[SEGV];
#pragma unroll
    for (int k = 0; k < SEGV; ++k) {
        int ya = y0 + k + RBOX + 1, ys = y0 + k - RBOX;
        VA[k] = h4[min(ya, HH - 1) * WW + xx];
        VS[k] = h4[max(ys, 0) * WW + xx];
    }
    __builtin_amdgcn_sched_barrier(0);
    float cx = (float)(min(xx + RBOX, WW - 1) - max(xx - RBOX, 0) + 1);
#pragma unroll
    for (int k = 0; k < SEGV; ++k) {
        int y = y0 + k;
        float cy = (float)(min(y + RBOX, HH - 1) - max(y - RBOX, 0) + 1);
        float inv = 1.0f / (cy * cx);
        float mI = s0 * inv, mp = s1 * inv;
        float cov = s2 * inv - mI * mp;
        float var = s3 * inv - mI * mI;
        float av = cov / (var + GFEPS);
        ab[y * WW + xx] = pbf2(av, mp - av * mI);
        int ya = y + RBOX + 1, ys = y - RBOX;
        bool oa = ya < HH, os = ys >= 0;
        s0 += (oa ? ublo(VA[k].x) : 0.f) - (os ? ublo(VS[k].x) : 0.f);
        s1 += (oa ? ubhi(VA[k].x) : 0.f) - (os ? ubhi(VS[k].x) : 0.f);
        s2 += (oa ? ublo(VA[k].y) : 0.f) - (os ? ublo(VS[k].y) : 0.f);
        s3 += (oa ? ubhi(VA[k].y) : 0.f) - (os ? ubhi(VS[k].y) : 0.f);
    }
}

// ---------- horizontal 121-box on packed (a,b) via LDS prefix sum (swizzled) ----------
__global__ __launch_bounds__(256) void k_boxh2_ps(const unsigned* __restrict__ ab,
                                                  unsigned* __restrict__ hab) {
    __shared__ float P0[LDSN], P1[LDSN];
    __shared__ float wtot[4][2];
    int tid = threadIdx.x;
    int base = blockIdx.x * WW + tid * 8;
    uint4 q0 = *(const uint4*)(ab + base);
    uint4 q1 = *(const uint4*)(ab + base + 4);
    unsigned uu[8] = {q0.x, q0.y, q0.z, q0.w, q1.x, q1.y, q1.z, q1.w};
    float e0[8], e1[8];
    float s0 = 0.f, s1 = 0.f;
#pragma unroll
    for (int j = 0; j < 8; ++j) {
        s0 += ublo(uu[j]); e0[j] = s0;
        s1 += ubhi(uu[j]); e1[j] = s1;
    }
    int lane = tid & 63, wv = tid >> 6;
    float i0 = s0, i1 = s1;
#pragma unroll
    for (int d = 1; d < 64; d <<= 1) {
        float u0 = __shfl_up(i0, d), u1 = __shfl_up(i1, d);
        if (lane >= d) { i0 += u0; i1 += u1; }
    }
    if (lane == 63) { wtot[wv][0] = i0; wtot[wv][1] = i1; }
    __syncthreads();
    float off0 = i0 - s0, off1 = i1 - s1;
    for (int w = 0; w < wv; ++w) { off0 += wtot[w][0]; off1 += wtot[w][1]; }
    int xb = tid * 8;
#pragma unroll
    for (int j = 0; j < 8; ++j) {
        int sw = SW(xb + j);
        P0[sw] = e0[j] + off0;
        P1[sw] = e1[j] + off1;
    }
    __syncthreads();
#pragma unroll
    for (int j = 0; j < 8; ++j) {
        int xx = xb + j;
        int hi = SW(min(xx + RBOX, WW - 1));
        int lo = xx - RBOX - 1;
        float b0 = 0.f, b1 = 0.f;
        if (lo >= 0) {
            int ls = SW(lo);
            b0 = P0[ls]; b1 = P1[ls];
        }
        hab[base + j] = pbf2(P0[hi] - b0, P1[hi] - b1);
    }
}

// ---------- vertical running-sum 121-box on packed (a,b) + recovery ----------
__global__ __launch_bounds__(256) void k_final_rs(const unsigned* __restrict__ hab,
                                                  const float* __restrict__ x,
                                                  const UdcpState* __restrict__ st,
                                                  float* __restrict__ out) {
    int xx = blockIdx.x * 256 + threadIdx.x;
    int y0 = blockIdx.y * SEGV;
    float A0 = __int_as_float(st->A_bits[0]);
    float A1 = __int_as_float(st->A_bits[1]);
    float A2 = __int_as_float(st->A_bits[2]);
    float a0[4] = {0.f, 0.f, 0.f, 0.f}, a1[4] = {0.f, 0.f, 0.f, 0.f};
#pragma unroll 16
    for (int j = 0; j <= 2 * RBOX; ++j) {
        int yy = y0 - RBOX + j;
        int yc = min(max(yy, 0), HH - 1);
        unsigned v = hab[yc * WW + xx];
        bool ok = (yy >= 0) && (yy < HH);
        int c = j & 3;
        a0[c] += ok ? ublo(v) : 0.f;
        a1[c] += ok ? ubhi(v) : 0.f;
    }
    float s0 = (a0[0] + a0[1]) + (a0[2] + a0[3]);
    float s1 = (a1[0] + a1[1]) + (a1[2] + a1[3]);
    unsigned VA[SEGV], VS[SEGV];
#pragma unroll
    for (int k = 0; k < SEGV; ++k) {
        int ya = y0 + k + RBOX + 1, ys = y0 + k - RBOX;
        VA[k] = hab[min(ya, HH - 1) * WW + xx];
        VS[k] = hab[max(ys, 0) * WW + xx];
    }
    __builtin_amdgcn_sched_barrier(0);
    float cx = (float)(min(xx + RBOX, WW - 1) - max(xx - RBOX, 0) + 1);
    int i0 = y0 * WW + xx;
    float R = x[i0], G = x[HWSZ + i0], B = x[2 * HWSZ + i0];
#pragma unroll
    for (int k = 0; k < SEGV; ++k) {
        int y = y0 + k;
        int i = y * WW + xx;
        float Rn, Gn, Bn;
        if (k < SEGV - 1) {
            Rn = x[i + WW]; Gn = x[HWSZ + i + WW]; Bn = x[2 * HWSZ + i + WW];
        }
        float cy = (float)(min(y + RBOX, HH - 1) - max(y - RBOX, 0) + 1);
        float inv = 1.0f / (cy * cx);
        float guide = 0.299f * R + 0.587f * G + 0.114f * B;
        float q = s0 * inv * guide + s1 * inv;
        float invt = 1.0f / fmaxf(q, T0C);
        float J0 = (R - A0) * invt + A0;
        float J1 = (G - A1) * invt + A1;
        float J2 = (B - A2) * invt + A2;
        __builtin_nontemporal_store(fminf(fmaxf(J0, 0.f), 1.f), &out[i]);
        __builtin_nontemporal_store(fminf(fmaxf(J1, 0.f), 1.f), &out[HWSZ + i]);
        __builtin_nontemporal_store(fminf(fmaxf(J2, 0.f), 1.f), &out[2 * HWSZ + i]);
        int ya = y + RBOX + 1, ys = y - RBOX;
        bool oa = ya < HH, os = ys >= 0;
        s0 += (oa ? ublo(VA[k]) : 0.f) - (os ? ublo(VS[k]) : 0.f);
        s1 += (oa ? ubhi(VA[k]) : 0.f) - (os ? ubhi(VS[k]) : 0.f);
        if (k < SEGV - 1) { R = Rn; G = Gn; B = Bn; }
    }
}

extern "C" void kernel_launch(void* const* d_in, const int* in_sizes, int n_in,
                              void* d_out, int out_size, void* d_ws, size_t ws_size,
                              hipStream_t stream) {
    const float* x = (const float*)d_in[0];
    float* out = (float*)d_out;
    char* ws = (char*)d_ws;
    UdcpState* st = (UdcpState*)ws;
    unsigned* MGB = (unsigned*)(ws + 65536);          // 16 MB
    float* DC = (float*)(MGB + HWSZ);                 // 16 MB
    uint2* H4 = (uint2*)(DC + HWSZ);                  // 32 MB
    unsigned* AB = (unsigned*)(H4 + HWSZ);            // 16 MB
    unsigned* HAB = AB + HWSZ;                        // 16 MB

    hipMemsetAsync(st, 0, sizeof(UdcpState), stream);

    dim3 blk(256);
    dim3 mgrid(WW / 256, HH / 8);
    dim3 vgrid(WW / 256, HH / SEGV);

    // dark channel + histogram + A
    k_minv8_gb2<<<mgrid, blk, 0, stream>>>(x, MGB);
    k_minh8_dc<<<HH, blk, 0, stream>>>(MGB, DC, st);
    k_tau<<<1, blk, 0, stream>>>(st);
    k_A2<<<HWSZ / 4096, blk, 0, stream>>>(DC, x, st);

    // guided filter (t computed inline from MGB)
    k_boxh4f2<<<HH, blk, 0, stream>>>(x, MGB, st, H4);
    k_boxv4<<<vgrid, blk, 0, stream>>>(H4, AB);
    k_boxh2_ps<<<HH, blk, 0, stream>>>(AB, HAB);
    k_final_rs<<<vgrid, blk, 0, stream>>>(HAB, x, st, out);
}

// Round 9
// 165.304 us; speedup vs baseline: 1.3033x; 1.3033x over previous
//
#include <hip/hip_runtime.h>
#include <math.h>

#define HH 2048
#define WW 2048
#define HWSZ (HH*WW)
#define SZL 512
#define HWL (SZL*SZL)
#define RBOX 60
#define RL 15
#define NBINS 2048
#define KTOP 4194
#define OMEGA 0.95f
#define T0C 0.1f
#define GFEPS 1e-4f
// LDS bank-conflict-killing swizzle for 8i+c access patterns
#define SW(i) ((i) + ((i) >> 3))
#define LDSN (WW + WW / 8)

typedef float nfloat4 __attribute__((ext_vector_type(4)));

struct UdcpState {
    int hist[NBINS];
    float tau;
    int A_bits[3];
};

__device__ __forceinline__ unsigned pbf2(float lo, float hi) {
    unsigned ul = __float_as_uint(lo), uh = __float_as_uint(hi);
    ul += 0x7FFFu + ((ul >> 16) & 1u);
    uh += 0x7FFFu + ((uh >> 16) & 1u);
    return (ul >> 16) | (uh & 0xFFFF0000u);
}
__device__ __forceinline__ float ublo(unsigned u) { return __uint_as_float(u << 16); }
__device__ __forceinline__ float ubhi(unsigned u) { return __uint_as_float(u & 0xFFFF0000u); }

// ---------- vertical 15-min of G and B separately -> packed bf16 pair ----------
__global__ __launch_bounds__(256) void k_minv8_gb2(const float* __restrict__ x,
                                                   unsigned* __restrict__ mgb) {
    int xx = blockIdx.x * 256 + threadIdx.x;
    int y0 = blockIdx.y * 8;
    float rg[22], rb[22];
#pragma unroll
    for (int j = 0; j < 22; ++j) {
        int y = y0 + j - 7;
        int yc = min(max(y, 0), HH - 1);
        int i = yc * WW + xx;
        float g = x[HWSZ + i], b = x[2 * HWSZ + i];
        bool ok = (y >= 0) && (y < HH);
        rg[j] = ok ? g : 1e30f;
        rb[j] = ok ? b : 1e30f;
    }
    float sg[15], sb[15];
    sg[14] = rg[14]; sb[14] = rb[14];
#pragma unroll
    for (int j = 13; j >= 0; --j) {
        sg[j] = fminf(rg[j], sg[j + 1]);
        sb[j] = fminf(rb[j], sb[j + 1]);
    }
    float pg = 1e30f, pb = 1e30f;
#pragma unroll
    for (int j = 0; j < 8; ++j) {
        float mg = fminf(sg[j], pg), mb = fminf(sb[j], pb);
        mgb[(y0 + j) * WW + xx] = pbf2(mg, mb);
        if (j < 7) { pg = fminf(pg, rg[15 + j]); pb = fminf(pb, rb[15 + j]); }
    }
}

// ---------- horizontal 15-min of min(mgv,mbv) -> dc, fused histogram ----------
__global__ __launch_bounds__(256) void k_minh8_dc(const unsigned* __restrict__ mgb,
                                                  float* __restrict__ dc,
                                                  UdcpState* st) {
    __shared__ int h[NBINS];
    for (int j = threadIdx.x; j < NBINS; j += 256) h[j] = 0;
    __syncthreads();
    int row = blockIdx.x;
    int xb = threadIdx.x * 8;
    const unsigned* rp = mgb + row * WW;
    float r[22];
#pragma unroll
    for (int j = 0; j < 22; ++j) {
        int xc = min(max(xb + j - 7, 0), WW - 1);
        unsigned u = rp[xc];
        float v = fminf(ublo(u), ubhi(u));
        bool ok = (xb + j - 7 >= 0) && (xb + j - 7 < WW);
        r[j] = ok ? v : 1e30f;
    }
    float suf[15];
    suf[14] = r[14];
#pragma unroll
    for (int j = 13; j >= 0; --j) suf[j] = fminf(r[j], suf[j + 1]);
    float pre = 1e30f;
    float o[8];
#pragma unroll
    for (int j = 0; j < 8; ++j) {
        o[j] = fminf(suf[j], pre);
        if (j < 7) pre = fminf(pre, r[15 + j]);
    }
    float* dr = dc + row * WW + xb;
    *(float4*)dr = make_float4(o[0], o[1], o[2], o[3]);
    *(float4*)(dr + 4) = make_float4(o[4], o[5], o[6], o[7]);
#pragma unroll
    for (int j = 0; j < 8; ++j) {
        int b = (int)(o[j] * (float)NBINS);
        b = min(max(b, 0), NBINS - 1);
        atomicAdd(&h[b], 1);
    }
    __syncthreads();
    for (int j = threadIdx.x; j < NBINS; j += 256) {
        int v = h[j];
        if (v) atomicAdd(&st->hist[j], v);
    }
}

// ---------- k-th largest bin lower edge ----------
__global__ void k_tau(UdcpState* st) {
    __shared__ int csum[256];
    int tid = threadIdx.x;
    int hi = NBINS - 1 - 8 * tid;
    int local = 0;
    for (int k = 0; k < 8; ++k) local += st->hist[hi - k];
    csum[tid] = local;
    __syncthreads();
    if (tid == 0) {
        int cum = 0;
        float tau = 0.f;
        bool done = false;
        for (int c = 0; c < 256 && !done; ++c) {
            if (cum + csum[c] >= KTOP) {
                int h2 = NBINS - 1 - 8 * c;
                int cc = cum;
                for (int k = 0; k < 8; ++k) {
                    cc += st->hist[h2 - k];
                    if (cc >= KTOP) {
                        tau = (float)(h2 - k) / (float)NBINS;
                        done = true;
                        break;
                    }
                }
            } else {
                cum += csum[c];
            }
        }
        st->tau = tau;
    }
}

// ---------- atmospheric light: block-level reduce, few atomics ----------
__global__ __launch_bounds__(256) void k_A2(const float* __restrict__ dc,
                                            const float* __restrict__ x,
                                            UdcpState* st) {
    __shared__ float r0[256], r1[256], r2[256];
    __shared__ int anyflag;
    if (threadIdx.x == 0) anyflag = 0;
    __syncthreads();
    float tau = st->tau;
    const float4* dc4 = (const float4*)dc;
    int base4 = blockIdx.x * 1024;
    float m0 = -1e30f, m1 = -1e30f, m2 = -1e30f;
    bool found = false;
#pragma unroll
    for (int k = 0; k < 4; ++k) {
        int q = base4 + k * 256 + threadIdx.x;
        float4 v = dc4[q];
        float dv[4] = {v.x, v.y, v.z, v.w};
#pragma unroll
        for (int c = 0; c < 4; ++c) {
            if (dv[c] >= tau) {
                int i = q * 4 + c;
                m0 = fmaxf(m0, x[i]);
                m1 = fmaxf(m1, x[HWSZ + i]);
                m2 = fmaxf(m2, x[2 * HWSZ + i]);
                found = true;
            }
        }
    }
    if (found) anyflag = 1;
    __syncthreads();
    if (!anyflag) return;
    r0[threadIdx.x] = m0; r1[threadIdx.x] = m1; r2[threadIdx.x] = m2;
    __syncthreads();
    for (int s = 128; s > 0; s >>= 1) {
        if (threadIdx.x < s) {
            r0[threadIdx.x] = fmaxf(r0[threadIdx.x], r0[threadIdx.x + s]);
            r1[threadIdx.x] = fmaxf(r1[threadIdx.x], r1[threadIdx.x + s]);
            r2[threadIdx.x] = fmaxf(r2[threadIdx.x], r2[threadIdx.x + s]);
        }
        __syncthreads();
    }
    if (threadIdx.x == 0 && r0[0] > -1e29f) {
        atomicMax(&st->A_bits[0], __float_as_int(r0[0]));
        atomicMax(&st->A_bits[1], __float_as_int(r1[0]));
        atomicMax(&st->A_bits[2], __float_as_int(r2[0]));
    }
}

// ---------- downsample-H: t from mgb, guide from x, 4 fields, 4x col-sum ----------
// one block per full-res row; writes DH[row][Xlow] = sum_{4 cols} {g,t,g*t,g*g}
__global__ __launch_bounds__(256) void k_downh(
        const float* __restrict__ x, const unsigned* __restrict__ mgb,
        const UdcpState* __restrict__ st, float4* __restrict__ dh) {
    __shared__ float mrow[LDSN];
    int tid = threadIdx.x;
    int base = blockIdx.x * WW + tid * 8;
    int xb = tid * 8;
    float iA1 = 1.0f / __int_as_float(st->A_bits[1]);
    float iA2 = 1.0f / __int_as_float(st->A_bits[2]);
    {
        uint4 ua = *(const uint4*)(mgb + base);
        uint4 ub = *(const uint4*)(mgb + base + 4);
        unsigned uu[8] = {ua.x, ua.y, ua.z, ua.w, ub.x, ub.y, ub.z, ub.w};
#pragma unroll
        for (int j = 0; j < 8; ++j)
            mrow[SW(xb + j)] = fminf(ublo(uu[j]) * iA1, ubhi(uu[j]) * iA2);
    }
    float4 Ra = *(const float4*)(x + base), Rb = *(const float4*)(x + base + 4);
    float4 Ga = *(const float4*)(x + HWSZ + base), Gb = *(const float4*)(x + HWSZ + base + 4);
    float4 Ba = *(const float4*)(x + 2 * HWSZ + base), Bb = *(const float4*)(x + 2 * HWSZ + base + 4);
    float Rv[8] = {Ra.x, Ra.y, Ra.z, Ra.w, Rb.x, Rb.y, Rb.z, Rb.w};
    float Gv[8] = {Ga.x, Ga.y, Ga.z, Ga.w, Gb.x, Gb.y, Gb.z, Gb.w};
    float Bv[8] = {Ba.x, Ba.y, Ba.z, Ba.w, Bb.x, Bb.y, Bb.z, Bb.w};
    __syncthreads();
    float tv[8];
    {
        float r[22];
#pragma unroll
        for (int j = 0; j < 22; ++j) {
            int xc = min(max(xb + j - 7, 0), WW - 1);
            float v = mrow[SW(xc)];
            bool ok = (xb + j - 7 >= 0) && (xb + j - 7 < WW);
            r[j] = ok ? v : 1e30f;
        }
        float suf[15];
        suf[14] = r[14];
#pragma unroll
        for (int j = 13; j >= 0; --j) suf[j] = fminf(r[j], suf[j + 1]);
        float pre = 1e30f;
#pragma unroll
        for (int j = 0; j < 8; ++j) {
            tv[j] = 1.0f - OMEGA * fminf(suf[j], pre);
            if (j < 7) pre = fminf(pre, r[15 + j]);
        }
    }
    float4 o0 = make_float4(0.f, 0.f, 0.f, 0.f);
    float4 o1 = make_float4(0.f, 0.f, 0.f, 0.f);
#pragma unroll
    for (int j = 0; j < 8; ++j) {
        float g = 0.299f * Rv[j] + 0.587f * Gv[j] + 0.114f * Bv[j];
        float t = tv[j];
        if (j < 4) { o0.x += g; o0.y += t; o0.z += g * t; o0.w += g * g; }
        else       { o1.x += g; o1.y += t; o1.z += g * t; o1.w += g * g; }
    }
    int ob = blockIdx.x * SZL + tid * 2;
    dh[ob] = o0;
    dh[ob + 1] = o1;
}

// ---------- downsample-V: 4-row sums -> block means (/16) at 512x512 ----------
__global__ __launch_bounds__(256) void k_downv(const float4* __restrict__ dh,
                                               float4* __restrict__ dl) {
    int idx = blockIdx.x * 256 + threadIdx.x;
    int X = idx & (SZL - 1), Y = idx >> 9;
    float4 s = make_float4(0.f, 0.f, 0.f, 0.f);
#pragma unroll
    for (int r = 0; r < 4; ++r) {
        float4 v = dh[(4 * Y + r) * SZL + X];
        s.x += v.x; s.y += v.y; s.z += v.z; s.w += v.w;
    }
    const float inv16 = 1.0f / 16.0f;
    dl[idx] = make_float4(s.x * inv16, s.y * inv16, s.z * inv16, s.w * inv16);
}

// ---------- low-res H-box (31 taps, direct) on 4 fields ----------
__global__ __launch_bounds__(256) void kl_bh4(const float4* __restrict__ dl,
                                              float4* __restrict__ hl) {
    int idx = blockIdx.x * 256 + threadIdx.x;
    int X = idx & (SZL - 1), Y = idx >> 9;
    float4 s = make_float4(0.f, 0.f, 0.f, 0.f);
#pragma unroll
    for (int d = -RL; d <= RL; ++d) {
        int XX = min(max(X + d, 0), SZL - 1);
        float4 v = dl[Y * SZL + XX];
        bool ok = (X + d >= 0) && (X + d < SZL);
        s.x += ok ? v.x : 0.f; s.y += ok ? v.y : 0.f;
        s.z += ok ? v.z : 0.f; s.w += ok ? v.w : 0.f;
    }
    hl[idx] = s;
}

// ---------- low-res V-box + a/b ----------
__global__ __launch_bounds__(256) void kl_bv4ab(const float4* __restrict__ hl,
                                                float2* __restrict__ abl) {
    int idx = blockIdx.x * 256 + threadIdx.x;
    int X = idx & (SZL - 1), Y = idx >> 9;
    float4 s = make_float4(0.f, 0.f, 0.f, 0.f);
#pragma unroll
    for (int d = -RL; d <= RL; ++d) {
        int YY = min(max(Y + d, 0), SZL - 1);
        float4 v = hl[YY * SZL + X];
        bool ok = (Y + d >= 0) && (Y + d < SZL);
        s.x += ok ? v.x : 0.f; s.y += ok ? v.y : 0.f;
        s.z += ok ? v.z : 0.f; s.w += ok ? v.w : 0.f;
    }
    float CX = (float)(min(X + RL, SZL - 1) - max(X - RL, 0) + 1);
    float CY = (float)(min(Y + RL, SZL - 1) - max(Y - RL, 0) + 1);
    float inv = 1.0f / (CX * CY);
    float mI = s.x * inv, mp = s.y * inv;
    float cov = s.z * inv - mI * mp;
    float var = s.w * inv - mI * mI;
    float a = cov / (var + GFEPS);
    abl[idx] = make_float2(a, mp - a * mI);
}

// ---------- low-res H-box on (a,b) ----------
__global__ __launch_bounds__(256) void kl_bh2(const float2* __restrict__ abl,
                                              float2* __restrict__ habl) {
    int idx = blockIdx.x * 256 + threadIdx.x;
    int X = idx & (SZL - 1), Y = idx >> 9;
    float sa = 0.f, sb = 0.f;
#pragma unroll
    for (int d = -RL; d <= RL; ++d) {
        int XX = min(max(X + d, 0), SZL - 1);
        float2 v = abl[Y * SZL + XX];
        bool ok = (X + d >= 0) && (X + d < SZL);
        sa += ok ? v.x : 0.f; sb += ok ? v.y : 0.f;
    }
    habl[idx] = make_float2(sa, sb);
}

// ---------- low-res V-box on (a,b) -> meanA, meanB ----------
__global__ __launch_bounds__(256) void kl_bv2(const float2* __restrict__ habl,
                                              float2* __restrict__ mab) {
    int idx = blockIdx.x * 256 + threadIdx.x;
    int X = idx & (SZL - 1), Y = idx >> 9;
    float sa = 0.f, sb = 0.f;
#pragma unroll
    for (int d = -RL; d <= RL; ++d) {
        int YY = min(max(Y + d, 0), SZL - 1);
        float2 v = habl[YY * SZL + X];
        bool ok = (Y + d >= 0) && (Y + d < SZL);
        sa += ok ? v.x : 0.f; sb += ok ? v.y : 0.f;
    }
    float CX = (float)(min(X + RL, SZL - 1) - max(X - RL, 0) + 1);
    float CY = (float)(min(Y + RL, SZL - 1) - max(Y - RL, 0) + 1);
    float inv = 1.0f / (CX * CY);
    mab[idx] = make_float2(sa * inv, sb * inv);
}

// ---------- final: bilinear-upsample meanA/meanB, recover, clip ----------
__global__ __launch_bounds__(256) void k_final_up(const float2* __restrict__ mab,
                                                  const float* __restrict__ x,
                                                  const UdcpState* __restrict__ st,
                                                  float* __restrict__ out) {
    int p = (blockIdx.x * 256 + threadIdx.x) * 4;
    int y = p >> 11, x0 = p & (WW - 1);
    float A0 = __int_as_float(st->A_bits[0]);
    float A1 = __int_as_float(st->A_bits[1]);
    float A2 = __int_as_float(st->A_bits[2]);
    float4 R = *(const float4*)(x + p);
    float4 G = *(const float4*)(x + HWSZ + p);
    float4 B = *(const float4*)(x + 2 * HWSZ + p);
    float Rv[4] = {R.x, R.y, R.z, R.w};
    float Gv[4] = {G.x, G.y, G.z, G.w};
    float Bv[4] = {B.x, B.y, B.z, B.w};
    // Y interp (shared by the 4 px)
    float Yf = (float)y * 0.25f - 0.375f;
    float Y0f = floorf(Yf);
    float wy = Yf - Y0f;
    int Y0 = (int)Y0f;
    if (Y0 < 0) { Y0 = 0; wy = 0.f; }
    if (Y0 > SZL - 2) { Y0 = SZL - 2; wy = 1.f; }
    float o0[4], o1[4], o2[4];
#pragma unroll
    for (int i = 0; i < 4; ++i) {
        float Xf = (float)(x0 + i) * 0.25f - 0.375f;
        float X0f = floorf(Xf);
        float wx = Xf - X0f;
        int X0 = (int)X0f;
        if (X0 < 0) { X0 = 0; wx = 0.f; }
        if (X0 > SZL - 2) { X0 = SZL - 2; wx = 1.f; }
        float2 m00 = mab[Y0 * SZL + X0],       m01 = mab[Y0 * SZL + X0 + 1];
        float2 m10 = mab[(Y0 + 1) * SZL + X0], m11 = mab[(Y0 + 1) * SZL + X0 + 1];
        float ma = (1.f - wy) * ((1.f - wx) * m00.x + wx * m01.x)
                 + wy * ((1.f - wx) * m10.x + wx * m11.x);
        float mb = (1.f - wy) * ((1.f - wx) * m00.y + wx * m01.y)
                 + wy * ((1.f - wx) * m10.y + wx * m11.y);
        float guide = 0.299f * Rv[i] + 0.587f * Gv[i] + 0.114f * Bv[i];
        float q = ma * guide + mb;
        float invt = 1.0f / fmaxf(q, T0C);
        o0[i] = fminf(fmaxf((Rv[i] - A0) * invt + A0, 0.f), 1.f);
        o1[i] = fminf(fmaxf((Gv[i] - A1) * invt + A1, 0.f), 1.f);
        o2[i] = fminf(fmaxf((Bv[i] - A2) * invt + A2, 0.f), 1.f);
    }
    nfloat4 J0 = {o0[0], o0[1], o0[2], o0[3]};
    nfloat4 J1 = {o1[0], o1[1], o1[2], o1[3]};
    nfloat4 J2 = {o2[0], o2[1], o2[2], o2[3]};
    __builtin_nontemporal_store(J0, (nfloat4*)(out + p));
    __builtin_nontemporal_store(J1, (nfloat4*)(out + HWSZ + p));
    __builtin_nontemporal_store(J2, (nfloat4*)(out + 2 * HWSZ + p));
}

extern "C" void kernel_launch(void* const* d_in, const int* in_sizes, int n_in,
                              void* d_out, int out_size, void* d_ws, size_t ws_size,
                              hipStream_t stream) {
    const float* x = (const float*)d_in[0];
    float* out = (float*)d_out;
    char* ws = (char*)d_ws;
    UdcpState* st = (UdcpState*)ws;
    unsigned* MGB = (unsigned*)(ws + 65536);      // 16 MB
    float* DC = (float*)(MGB + HWSZ);             // 16 MB
    float4* DH = (float4*)(DC + HWSZ);            // 16 MB (2048 x 512)
    float4* DL = DH + HH * SZL;                   // 4 MB  (512 x 512)
    float4* HL = DL + HWL;                        // 4 MB
    float2* ABL = (float2*)(HL + HWL);            // 2 MB
    float2* HABL = ABL + HWL;                     // 2 MB
    float2* MAB = HABL + HWL;                     // 2 MB

    hipMemsetAsync(st, 0, sizeof(UdcpState), stream);

    dim3 blk(256);
    dim3 mgrid(WW / 256, HH / 8);

    // dark channel + histogram + A
    k_minv8_gb2<<<mgrid, blk, 0, stream>>>(x, MGB);
    k_minh8_dc<<<HH, blk, 0, stream>>>(MGB, DC, st);
    k_tau<<<1, blk, 0, stream>>>(st);
    k_A2<<<HWSZ / 4096, blk, 0, stream>>>(DC, x, st);

    // fast guided filter: downsample 4x, box at 512^2, upsample in final
    k_downh<<<HH, blk, 0, stream>>>(x, MGB, st, DH);
    k_downv<<<HWL / 256, blk, 0, stream>>>(DH, DL);
    kl_bh4<<<HWL / 256, blk, 0, stream>>>(DL, HL);
    kl_bv4ab<<<HWL / 256, blk, 0, stream>>>(HL, ABL);
    kl_bh2<<<HWL / 256, blk, 0, stream>>>(ABL, HABL);
    kl_bv2<<<HWL / 256, blk, 0, stream>>>(HABL, MAB);
    k_final_up<<<HWSZ / 1024, blk, 0, stream>>>(MAB, x, st, out);
}